// Round 1
// baseline (616.833 us; speedup 1.0000x reference)
//
#include <hip/hip_runtime.h>
#include <hip/hip_bf16.h>
#include <cstdint>

#define LM1   3
#define BDIM  64
#define NROW  (LM1 * BDIM)     // 192
#define DDIM  512
#define NW    (DDIM * DDIM)    // 262144 elements per w-row
#define NW4   (NW / 4)         // 65536 float4 per w-row
#define WT    1024             // threads per wstats block

// ---------- monotone float<->uint transform (total order) ----------
__device__ __forceinline__ uint32_t mono(float x) {
    uint32_t u = __float_as_uint(x);
    return (u & 0x80000000u) ? ~u : (u | 0x80000000u);
}
__device__ __forceinline__ float unmono(uint32_t u) {
    uint32_t v = (u & 0x80000000u) ? (u & 0x7FFFFFFFu) : ~u;
    return __uint_as_float(v);
}

// ---------- block-wide "find bin containing rank" ----------
// hist[nb] in LDS; finds smallest bin s.t. cumsum > rank.
// Writes *out_bin, *out_rem (rank within bin). All threads must call.
__device__ void block_select(const uint32_t* hist, int nb, uint32_t rank,
                             uint32_t* sbuf, uint32_t* out_bin, uint32_t* out_rem,
                             int tid) {
    const int NT = WT;
    int per = (nb + NT - 1) / NT;
    int base = tid * per;
    uint32_t s = 0;
    for (int i = 0; i < per; ++i) {
        int idx = base + i;
        if (idx < nb) s += hist[idx];
    }
    sbuf[tid] = s;
    __syncthreads();
    uint32_t run = s;
    for (int off = 1; off < NT; off <<= 1) {
        uint32_t add = (tid >= off) ? sbuf[tid - off] : 0u;
        __syncthreads();
        run += add;
        sbuf[tid] = run;
        __syncthreads();
    }
    uint32_t incl = run;
    uint32_t excl = incl - s;
    if (rank >= excl && rank < incl) {
        uint32_t rem = rank - excl;
        for (int i = 0; i < per; ++i) {
            int idx = base + i;
            if (idx >= nb) break;
            uint32_t c = hist[idx];
            if (rem < c) { *out_bin = (uint32_t)idx; *out_rem = rem; break; }
            rem -= c;
        }
    }
    __syncthreads();
}

// ---------- w-row robust stats: one block per (l,b) row ----------
// feat layout per row (16 floats): [w_med, w_mad, w_min, w_q25, w_q50, w_q75,
//  w_max, b_med, b_mad, b_min, b_q25, b_q50, b_q75, b_max, g_mean, 0]
__global__ __launch_bounds__(WT) void wstats_kernel(const float* __restrict__ wsrc,
                                                    float* __restrict__ feat) {
    const int row = blockIdx.x;
    const int tid = threadIdx.x;
    const float4* __restrict__ p4 = (const float4*)(wsrc + (size_t)row * NW);

    __shared__ uint32_t hist[6 * 2048];   // 48 KB, reused for all levels
    __shared__ uint32_t sbuf[WT];         // 4 KB scan / reduce buffer
    __shared__ uint32_t bin1[6], rem1[6], bin2[6], rem2[6], bin3[6];
    __shared__ float s_med;

    // ---- Phase A: sweep 1 — sum, min, max, level-1 histogram (12 bits) ----
    for (int i = tid; i < 4096; i += WT) hist[i] = 0;
    __syncthreads();
    float sum = 0.f;
    uint32_t mn = 0xFFFFFFFFu, mx = 0u;
    for (int i = tid; i < NW4; i += WT) {
        float4 v = p4[i];
        float xs[4] = {v.x, v.y, v.z, v.w};
        #pragma unroll
        for (int c = 0; c < 4; ++c) {
            float x = xs[c];
            sum += x;
            uint32_t u = mono(x);
            mn = mn < u ? mn : u;
            mx = mx > u ? mx : u;
            atomicAdd(&hist[u >> 20], 1u);
        }
    }
    float* sbf = (float*)sbuf;
    sbf[tid] = sum; __syncthreads();
    for (int off = WT / 2; off > 0; off >>= 1) {
        if (tid < off) sbf[tid] += sbf[tid + off];
        __syncthreads();
    }
    if (tid == 0) feat[row * 16 + 14] = sbf[0] * (1.0f / (float)NW);
    __syncthreads();
    sbuf[tid] = mn; __syncthreads();
    for (int off = WT / 2; off > 0; off >>= 1) {
        if (tid < off) sbuf[tid] = sbuf[tid] < sbuf[tid + off] ? sbuf[tid] : sbuf[tid + off];
        __syncthreads();
    }
    if (tid == 0) feat[row * 16 + 2] = unmono(sbuf[0]);
    __syncthreads();
    sbuf[tid] = mx; __syncthreads();
    for (int off = WT / 2; off > 0; off >>= 1) {
        if (tid < off) sbuf[tid] = sbuf[tid] > sbuf[tid + off] ? sbuf[tid] : sbuf[tid + off];
        __syncthreads();
    }
    if (tid == 0) feat[row * 16 + 6] = unmono(sbuf[0]);
    __syncthreads();

    // ---- Phase B: level-1 select for the 6 interior ranks ----
    const uint32_t RANKS[6] = {65535u, 65536u, 131071u, 131072u, 196607u, 196608u};
    for (int k = 0; k < 6; ++k)
        block_select(hist, 4096, RANKS[k], sbuf, &bin1[k], &rem1[k], tid);

    // ---- Phase C: sweep 2 — level-2 histograms (next 11 bits) ----
    uint32_t b1r[6];
    #pragma unroll
    for (int k = 0; k < 6; ++k) b1r[k] = bin1[k];
    __syncthreads();
    for (int i = tid; i < 6 * 2048; i += WT) hist[i] = 0;
    __syncthreads();
    for (int i = tid; i < NW4; i += WT) {
        float4 v = p4[i];
        float xs[4] = {v.x, v.y, v.z, v.w};
        #pragma unroll
        for (int c = 0; c < 4; ++c) {
            uint32_t u = mono(xs[c]);
            uint32_t b = u >> 20;
            uint32_t m = (u >> 9) & 2047u;
            #pragma unroll
            for (int k = 0; k < 6; ++k)
                if (b == b1r[k]) atomicAdd(&hist[k * 2048 + m], 1u);
        }
    }
    __syncthreads();
    for (int k = 0; k < 6; ++k)
        block_select(hist + k * 2048, 2048, rem1[k], sbuf, &bin2[k], &rem2[k], tid);

    // ---- Phase E: sweep 3 — level-3 histograms (low 9 bits) ----
    uint32_t b2r[6];
    #pragma unroll
    for (int k = 0; k < 6; ++k) b2r[k] = bin2[k];
    __syncthreads();
    for (int i = tid; i < 6 * 512; i += WT) hist[i] = 0;
    __syncthreads();
    for (int i = tid; i < NW4; i += WT) {
        float4 v = p4[i];
        float xs[4] = {v.x, v.y, v.z, v.w};
        #pragma unroll
        for (int c = 0; c < 4; ++c) {
            uint32_t u = mono(xs[c]);
            uint32_t b = u >> 20;
            uint32_t m = (u >> 9) & 2047u;
            #pragma unroll
            for (int k = 0; k < 6; ++k)
                if (b == b1r[k] && m == b2r[k]) atomicAdd(&hist[k * 512 + (u & 511u)], 1u);
        }
    }
    __syncthreads();
    for (int k = 0; k < 6; ++k)
        block_select(hist + k * 512, 512, rem2[k], sbuf, &bin3[k], &rem1[k], tid);

    if (tid == 0) {
        float sv[6];
        #pragma unroll
        for (int k = 0; k < 6; ++k)
            sv[k] = unmono((bin1[k] << 20) | (bin2[k] << 9) | bin3[k]);
        float* f = feat + row * 16;
        f[0]  = sv[2];                         // lower median
        f[3]  = 0.25f * sv[0] + 0.75f * sv[1]; // q=0.25
        f[4]  = 0.5f * (sv[2] + sv[3]);        // q=0.50
        f[5]  = 0.75f * sv[4] + 0.25f * sv[5]; // q=0.75
        f[15] = 0.0f;                          // g_mad
        s_med = sv[2];
    }
    __syncthreads();
    const float med = s_med;

    // ---- Phases F-H: MAD = rank-131071 of |x - med| (3 sweeps) ----
    for (int i = tid; i < 4096; i += WT) hist[i] = 0;
    __syncthreads();
    for (int i = tid; i < NW4; i += WT) {
        float4 v = p4[i];
        float xs[4] = {v.x, v.y, v.z, v.w};
        #pragma unroll
        for (int c = 0; c < 4; ++c) {
            uint32_t u = __float_as_uint(fabsf(xs[c] - med));
            atomicAdd(&hist[u >> 20], 1u);
        }
    }
    __syncthreads();
    block_select(hist, 4096, 131071u, sbuf, &bin1[0], &rem1[0], tid);
    const uint32_t mb1 = bin1[0];
    const uint32_t mr1 = rem1[0];
    __syncthreads();
    for (int i = tid; i < 2048; i += WT) hist[i] = 0;
    __syncthreads();
    for (int i = tid; i < NW4; i += WT) {
        float4 v = p4[i];
        float xs[4] = {v.x, v.y, v.z, v.w};
        #pragma unroll
        for (int c = 0; c < 4; ++c) {
            uint32_t u = __float_as_uint(fabsf(xs[c] - med));
            if ((u >> 20) == mb1) atomicAdd(&hist[(u >> 9) & 2047u], 1u);
        }
    }
    __syncthreads();
    block_select(hist, 2048, mr1, sbuf, &bin2[0], &rem2[0], tid);
    const uint32_t mb2 = bin2[0];
    const uint32_t mr2 = rem2[0];
    __syncthreads();
    for (int i = tid; i < 512; i += WT) hist[i] = 0;
    __syncthreads();
    for (int i = tid; i < NW4; i += WT) {
        float4 v = p4[i];
        float xs[4] = {v.x, v.y, v.z, v.w};
        #pragma unroll
        for (int c = 0; c < 4; ++c) {
            uint32_t u = __float_as_uint(fabsf(xs[c] - med));
            if ((u >> 20) == mb1 && ((u >> 9) & 2047u) == mb2)
                atomicAdd(&hist[u & 511u], 1u);
        }
    }
    __syncthreads();
    block_select(hist, 512, mr2, sbuf, &bin3[0], &rem1[0], tid);
    if (tid == 0)
        feat[row * 16 + 1] = __uint_as_float((mb1 << 20) | (mb2 << 9) | bin3[0]);
}

// ---------- in-LDS bitonic sort of 512 floats, 256 threads ----------
__device__ void bitonic512(float* a, int tid) {
    for (int k = 2; k <= 512; k <<= 1) {
        for (int j = k >> 1; j > 0; j >>= 1) {
            __syncthreads();
            for (int i = tid; i < 512; i += 256) {
                int ixj = i ^ j;
                if (ixj > i) {
                    float x = a[i], y = a[ixj];
                    bool up = ((i & k) == 0);
                    if ((x > y) == up) { a[i] = y; a[ixj] = x; }
                }
            }
        }
    }
    __syncthreads();
}

// ---------- b-row robust stats: one block per (l,b) row ----------
__global__ __launch_bounds__(256) void bstats_kernel(const float* __restrict__ bsrc,
                                                     float* __restrict__ feat) {
    const int row = blockIdx.x;
    const int tid = threadIdx.x;
    __shared__ float a[512];
    __shared__ float d[512];
    const float* p = bsrc + (size_t)row * 512;
    for (int i = tid; i < 512; i += 256) a[i] = p[i];
    bitonic512(a, tid);
    const float med = a[255];
    if (tid == 0) {
        float* f = feat + row * 16;
        f[7]  = med;
        f[9]  = a[0];
        f[10] = 0.25f * a[127] + 0.75f * a[128];
        f[11] = 0.5f * (a[255] + a[256]);
        f[12] = 0.75f * a[383] + 0.25f * a[384];
        f[13] = a[511];
    }
    __syncthreads();
    for (int i = tid; i < 512; i += 256) d[i] = fabsf(a[i] - med);
    bitonic512(d, tid);
    if (tid == 0) feat[row * 16 + 8] = d[255];
}

// ---------- MLP head: one block per (l,b) row ----------
__global__ __launch_bounds__(256) void mlp_kernel(
    const float* __restrict__ feat,
    const float* __restrict__ fc1_w, const float* __restrict__ fc1_b,
    const float* __restrict__ ln_w,  const float* __restrict__ ln_b,
    const float* __restrict__ gate_w, const float* __restrict__ gate_b,
    const float* __restrict__ fco_w,  const float* __restrict__ fco_b,
    const float* __restrict__ scale,  float* __restrict__ out) {
    const int row = blockIdx.x;
    const int tid = threadIdx.x;
    const int l = row >> 6;
    __shared__ float x[16], h[64], hg[64], stats[2];

    if (tid < 16) x[tid] = feat[row * 16 + tid];
    __syncthreads();
    if (tid == 0) {
        float mu = 0.f;
        for (int i = 0; i < 16; ++i) mu += x[i];
        mu *= (1.f / 16.f);
        float var = 0.f;
        for (int i = 0; i < 16; ++i) { float dd = x[i] - mu; var += dd * dd; }
        var *= (1.f / 16.f);
        stats[0] = mu; stats[1] = rsqrtf(var + 1e-5f);
    }
    __syncthreads();
    if (tid < 16) x[tid] = (x[tid] - stats[0]) * stats[1];
    __syncthreads();
    if (tid < 64) {
        const float* w = fc1_w + ((size_t)l * 64 + tid) * 16;
        float acc = fc1_b[l * 64 + tid];
        #pragma unroll
        for (int i = 0; i < 16; ++i) acc += x[i] * w[i];
        h[tid] = acc;
    }
    __syncthreads();
    if (tid == 0) {
        float mu = 0.f;
        for (int i = 0; i < 64; ++i) mu += h[i];
        mu *= (1.f / 64.f);
        float var = 0.f;
        for (int i = 0; i < 64; ++i) { float dd = h[i] - mu; var += dd * dd; }
        var *= (1.f / 64.f);
        stats[0] = mu; stats[1] = rsqrtf(var + 1e-5f);
    }
    __syncthreads();
    if (tid < 64) {
        float v = (h[tid] - stats[0]) * stats[1] * ln_w[l * 64 + tid] + ln_b[l * 64 + tid];
        h[tid] = 0.5f * v * (1.0f + erff(v * 0.70710678118654752f));  // exact GELU
    }
    __syncthreads();
    if (tid < 64) {
        const float* w = gate_w + ((size_t)l * 64 + tid) * 64;
        float acc = gate_b[l * 64 + tid];
        #pragma unroll
        for (int i = 0; i < 64; ++i) acc += h[i] * w[i];
        float g = 1.0f / (1.0f + expf(-acc));
        hg[tid] = h[tid] * g;
    }
    __syncthreads();
    const float sc = scale[l];
    for (int o = tid; o < 512; o += 256) {
        const float* w = fco_w + ((size_t)l * 512 + o) * 64;
        float acc = fco_b[l * 512 + o];
        #pragma unroll
        for (int i = 0; i < 64; ++i) acc += hg[i] * w[i];
        out[(size_t)row * 512 + o] = sinf(acc) * sc + 1.0f;
    }
}

extern "C" void kernel_launch(void* const* d_in, const int* in_sizes, int n_in,
                              void* d_out, int out_size, void* d_ws, size_t ws_size,
                              hipStream_t stream) {
    const float* ws_in  = (const float*)d_in[0];
    const float* bs_in  = (const float*)d_in[1];
    // d_in[2] (w_last) and d_in[3] (b_last) are unused by the reference.
    const float* fc1_w  = (const float*)d_in[4];
    const float* fc1_b  = (const float*)d_in[5];
    const float* ln_w   = (const float*)d_in[6];
    const float* ln_b   = (const float*)d_in[7];
    const float* gate_w = (const float*)d_in[8];
    const float* gate_b = (const float*)d_in[9];
    const float* fco_w  = (const float*)d_in[10];
    const float* fco_b  = (const float*)d_in[11];
    const float* scale  = (const float*)d_in[12];
    float* out  = (float*)d_out;
    float* feat = (float*)d_ws;   // 192 rows x 16 features

    hipLaunchKernelGGL(wstats_kernel, dim3(NROW), dim3(WT), 0, stream, ws_in, feat);
    hipLaunchKernelGGL(bstats_kernel, dim3(NROW), dim3(256), 0, stream, bs_in, feat);
    hipLaunchKernelGGL(mlp_kernel, dim3(NROW), dim3(256), 0, stream,
                       feat, fc1_w, fc1_b, ln_w, ln_b, gate_w, gate_b,
                       fco_w, fco_b, scale, out);
}

// Round 2
// 502.704 us; speedup vs baseline: 1.2270x; 1.2270x over previous
//
#include <hip/hip_runtime.h>
#include <cstdint>

#define LM1   3
#define BDIM  64
#define NROW  (LM1 * BDIM)     // 192
#define DDIM  512
#define NW    (DDIM * DDIM)    // 262144 elements per w-row
#define NW4   (NW / 4)         // 65536 float4 per w-row
#define WT    1024             // threads per wstats block
#define CAP   30720            // LDS collect capacity (words)

// ---------- monotone float<->uint transform (total order) ----------
__device__ __forceinline__ uint32_t mono(float x) {
    uint32_t u = __float_as_uint(x);
    return (u & 0x80000000u) ? ~u : (u | 0x80000000u);
}
__device__ __forceinline__ float unmono(uint32_t u) {
    uint32_t v = (u & 0x80000000u) ? (u & 0x7FFFFFFFu) : ~u;
    return __uint_as_float(v);
}

// ---------- block-wide "find bin containing rank" ----------
__device__ void block_select(const uint32_t* hist, int nb, uint32_t rank,
                             uint32_t* sbuf, uint32_t* out_bin, uint32_t* out_rem,
                             int tid) {
    const int NT = WT;
    int per = (nb + NT - 1) / NT;
    int base = tid * per;
    uint32_t s = 0;
    for (int i = 0; i < per; ++i) {
        int idx = base + i;
        if (idx < nb) s += hist[idx];
    }
    sbuf[tid] = s;
    __syncthreads();
    uint32_t run = s;
    for (int off = 1; off < NT; off <<= 1) {
        uint32_t add = (tid >= off) ? sbuf[tid - off] : 0u;
        __syncthreads();
        run += add;
        sbuf[tid] = run;
        __syncthreads();
    }
    uint32_t incl = run;
    uint32_t excl = incl - s;
    if (rank >= excl && rank < incl) {
        uint32_t rem = rank - excl;
        for (int i = 0; i < per; ++i) {
            int idx = base + i;
            if (idx >= nb) break;
            uint32_t c = hist[idx];
            if (rem < c) { *out_bin = (uint32_t)idx; *out_rem = rem; break; }
            rem -= c;
        }
    }
    __syncthreads();
}

// ---------- finish a rank from collected LDS values (levels 2+3) ----------
__device__ uint32_t refine_lds(const uint32_t* cbuf, uint32_t off, uint32_t cnt,
                               uint32_t rem, uint32_t b1,
                               uint32_t* hist2, uint32_t* sbuf,
                               uint32_t* stmp, int tid) {
    for (int i = tid; i < 2048; i += WT) hist2[i] = 0;
    __syncthreads();
    for (uint32_t i = tid; i < cnt; i += WT) {
        uint32_t u = cbuf[off + i];
        atomicAdd(&hist2[(u >> 9) & 2047u], 1u);
    }
    __syncthreads();
    block_select(hist2, 2048, rem, sbuf, &stmp[0], &stmp[1], tid);
    uint32_t b2 = stmp[0], r2 = stmp[1];
    __syncthreads();
    for (int i = tid; i < 512; i += WT) hist2[i] = 0;
    __syncthreads();
    for (uint32_t i = tid; i < cnt; i += WT) {
        uint32_t u = cbuf[off + i];
        if (((u >> 9) & 2047u) == b2) atomicAdd(&hist2[u & 511u], 1u);
    }
    __syncthreads();
    block_select(hist2, 512, r2, sbuf, &stmp[0], &stmp[1], tid);
    uint32_t b3 = stmp[0];
    __syncthreads();
    return (b1 << 20) | (b2 << 9) | b3;
}

// ---------- fallback: finish a rank with 2 global sweeps ----------
__device__ uint32_t refine_global(const float4* p4, float med, int mode,
                                  uint32_t b1, uint32_t rem,
                                  uint32_t* hist2, uint32_t* sbuf,
                                  uint32_t* stmp, int tid) {
    for (int i = tid; i < 2048; i += WT) hist2[i] = 0;
    __syncthreads();
    for (int it = 0; it < 64; ++it) {
        float4 v = p4[tid + it * WT];
        float xs[4] = {v.x, v.y, v.z, v.w};
        #pragma unroll
        for (int c = 0; c < 4; ++c) {
            uint32_t u = mode ? __float_as_uint(fabsf(xs[c] - med)) : mono(xs[c]);
            if ((u >> 20) == b1) atomicAdd(&hist2[(u >> 9) & 2047u], 1u);
        }
    }
    __syncthreads();
    block_select(hist2, 2048, rem, sbuf, &stmp[0], &stmp[1], tid);
    uint32_t b2 = stmp[0], r2 = stmp[1];
    __syncthreads();
    for (int i = tid; i < 512; i += WT) hist2[i] = 0;
    __syncthreads();
    for (int it = 0; it < 64; ++it) {
        float4 v = p4[tid + it * WT];
        float xs[4] = {v.x, v.y, v.z, v.w};
        #pragma unroll
        for (int c = 0; c < 4; ++c) {
            uint32_t u = mode ? __float_as_uint(fabsf(xs[c] - med)) : mono(xs[c]);
            if ((u >> 20) == b1 && ((u >> 9) & 2047u) == b2)
                atomicAdd(&hist2[u & 511u], 1u);
        }
    }
    __syncthreads();
    block_select(hist2, 512, r2, sbuf, &stmp[0], &stmp[1], tid);
    uint32_t b3 = stmp[0];
    __syncthreads();
    return (b1 << 20) | (b2 << 9) | b3;
}

// ---------- w-row robust stats: one block per (l,b) row, 4 global sweeps ----------
__global__ __launch_bounds__(WT) void wstats_kernel(const float* __restrict__ wsrc,
                                                    float* __restrict__ feat) {
    const int row = blockIdx.x;
    const int tid = threadIdx.x;
    const float4* __restrict__ p4 = (const float4*)(wsrc + (size_t)row * NW);

    // LDS carve: hist[4096] | cbuf[30720] | hist2[2048] | sbuf[1024] = 151552 B
    __shared__ uint32_t lds[4096 + CAP + 2048 + 1024];
    uint32_t* hist  = lds;
    uint32_t* cbuf  = lds + 4096;
    uint32_t* hist2 = lds + 4096 + CAP;
    uint32_t* sbuf  = lds + 4096 + CAP + 2048;
    __shared__ uint32_t s_bin[8], s_rem[8];
    __shared__ uint32_t s_dbin[8], s_cnt[8], s_off[9], s_cur[8], s_rdj[8];
    __shared__ uint32_t s_nd, s_T, stmp[2], s_sv[8];
    __shared__ float s_med;

    // ---- Sweep 1: sum + 12-bit histogram (4-deep load batches) ----
    for (int i = tid; i < 4096; i += WT) hist[i] = 0;
    __syncthreads();
    float sum = 0.f;
    {
        const float4* bp = p4 + tid;
        for (int it = 0; it < 64; it += 4) {
            float4 a0 = bp[(it + 0) * WT];
            float4 a1 = bp[(it + 1) * WT];
            float4 a2 = bp[(it + 2) * WT];
            float4 a3 = bp[(it + 3) * WT];
#define PROC(v) { float xs[4] = {v.x, v.y, v.z, v.w}; \
    _Pragma("unroll") for (int c = 0; c < 4; ++c) { \
        sum += xs[c]; uint32_t u = mono(xs[c]); atomicAdd(&hist[u >> 20], 1u); } }
            PROC(a0) PROC(a1) PROC(a2) PROC(a3)
#undef PROC
        }
    }
    {
        float* sbf = (float*)sbuf;
        sbf[tid] = sum; __syncthreads();
        for (int o = WT / 2; o > 0; o >>= 1) {
            if (tid < o) sbf[tid] += sbf[tid + o];
            __syncthreads();
        }
        if (tid == 0) feat[row * 16 + 14] = sbf[0] * (1.0f / (float)NW);
    }
    __syncthreads();

    // ---- Level-1 select for 8 ranks (min, q25 pair, med pair, q75 pair, max) ----
    const uint32_t RANKS[8] = {0u, 65535u, 65536u, 131071u, 131072u, 196607u, 196608u, 262143u};
    for (int k = 0; k < 8; ++k)
        block_select(hist, 4096, RANKS[k], sbuf, &s_bin[k], &s_rem[k], tid);

    if (tid == 0) {
        uint32_t nd = 0;
        for (int k = 0; k < 8; ++k) {
            uint32_t b = s_bin[k];
            int j = -1;
            for (uint32_t t = 0; t < nd; ++t) if (s_dbin[t] == b) { j = (int)t; break; }
            if (j < 0) { j = nd; s_dbin[nd] = b; s_cnt[nd] = hist[b]; nd++; }
            s_rdj[k] = (uint32_t)j;
        }
        s_off[0] = 0;
        for (uint32_t t = 0; t < nd; ++t) { s_off[t + 1] = s_off[t] + s_cnt[t]; s_cur[t] = 0; }
        s_nd = nd; s_T = s_off[nd];
    }
    __syncthreads();
    const uint32_t nd = s_nd, T = s_T;

    // ---- Sweep 2: collect candidate-bin values to LDS, finish in-LDS ----
    if (T <= CAP) {
        uint8_t* tbl = (uint8_t*)sbuf;   // 4096-entry bin -> (distinct idx + 1)
        for (int i = tid; i < 4096; i += WT) tbl[i] = 0;
        __syncthreads();
        if (tid < (int)nd) tbl[s_dbin[tid]] = (uint8_t)(tid + 1);
        __syncthreads();
        {
            const float4* bp = p4 + tid;
            for (int it = 0; it < 64; it += 4) {
                float4 a0 = bp[(it + 0) * WT];
                float4 a1 = bp[(it + 1) * WT];
                float4 a2 = bp[(it + 2) * WT];
                float4 a3 = bp[(it + 3) * WT];
#define PROC(v) { float xs[4] = {v.x, v.y, v.z, v.w}; \
    _Pragma("unroll") for (int c = 0; c < 4; ++c) { \
        uint32_t u = mono(xs[c]); uint32_t m = tbl[u >> 20]; \
        if (m) { uint32_t j = m - 1; uint32_t pos = atomicAdd(&s_cur[j], 1u); \
                 cbuf[s_off[j] + pos] = u; } } }
                PROC(a0) PROC(a1) PROC(a2) PROC(a3)
#undef PROC
            }
        }
        __syncthreads();
        for (int k = 0; k < 8; ++k) {
            uint32_t j = s_rdj[k];
            uint32_t u = refine_lds(cbuf, s_off[j], s_cnt[j], s_rem[k], s_bin[k],
                                    hist2, sbuf, stmp, tid);
            if (tid == 0) s_sv[k] = u;
            __syncthreads();
        }
    } else {  // safety fallback (not expected for Gaussian data)
        for (int k = 0; k < 8; ++k) {
            uint32_t u = refine_global(p4, 0.f, 0, s_bin[k], s_rem[k],
                                       hist2, sbuf, stmp, tid);
            if (tid == 0) s_sv[k] = u;
            __syncthreads();
        }
    }

    if (tid == 0) {
        float sv[8];
        #pragma unroll
        for (int k = 0; k < 8; ++k) sv[k] = unmono(s_sv[k]);
        float* f = feat + row * 16;
        f[0]  = sv[3];                          // lower median s[131071]
        f[2]  = sv[0];                          // min
        f[3]  = 0.25f * sv[1] + 0.75f * sv[2];  // q25
        f[4]  = 0.5f  * (sv[3] + sv[4]);        // q50
        f[5]  = 0.75f * sv[5] + 0.25f * sv[6];  // q75
        f[6]  = sv[7];                          // max
        f[15] = 0.0f;                           // g_mad
        s_med = sv[3];
    }
    __syncthreads();
    const float med = s_med;

    // ---- Sweep 3: 12-bit histogram of |x - med| ----
    for (int i = tid; i < 4096; i += WT) hist[i] = 0;
    __syncthreads();
    {
        const float4* bp = p4 + tid;
        for (int it = 0; it < 64; it += 4) {
            float4 a0 = bp[(it + 0) * WT];
            float4 a1 = bp[(it + 1) * WT];
            float4 a2 = bp[(it + 2) * WT];
            float4 a3 = bp[(it + 3) * WT];
#define PROC(v) { float xs[4] = {v.x, v.y, v.z, v.w}; \
    _Pragma("unroll") for (int c = 0; c < 4; ++c) { \
        uint32_t u = __float_as_uint(fabsf(xs[c] - med)); \
        atomicAdd(&hist[u >> 20], 1u); } }
            PROC(a0) PROC(a1) PROC(a2) PROC(a3)
#undef PROC
        }
    }
    __syncthreads();
    block_select(hist, 4096, 131071u, sbuf, &s_bin[0], &s_rem[0], tid);
    const uint32_t mb1 = s_bin[0], mrem = s_rem[0];
    const uint32_t mcnt = hist[mb1];
    __syncthreads();

    // ---- Sweep 4: collect MAD-bin values, finish in-LDS ----
    uint32_t madu;
    if (mcnt <= CAP) {
        if (tid == 0) s_cur[0] = 0;
        __syncthreads();
        const float4* bp = p4 + tid;
        for (int it = 0; it < 64; it += 4) {
            float4 a0 = bp[(it + 0) * WT];
            float4 a1 = bp[(it + 1) * WT];
            float4 a2 = bp[(it + 2) * WT];
            float4 a3 = bp[(it + 3) * WT];
#define PROC(v) { float xs[4] = {v.x, v.y, v.z, v.w}; \
    _Pragma("unroll") for (int c = 0; c < 4; ++c) { \
        uint32_t u = __float_as_uint(fabsf(xs[c] - med)); \
        if ((u >> 20) == mb1) { uint32_t pos = atomicAdd(&s_cur[0], 1u); cbuf[pos] = u; } } }
            PROC(a0) PROC(a1) PROC(a2) PROC(a3)
#undef PROC
        }
        __syncthreads();
        madu = refine_lds(cbuf, 0, mcnt, mrem, mb1, hist2, sbuf, stmp, tid);
    } else {
        madu = refine_global(p4, med, 1, mb1, mrem, hist2, sbuf, stmp, tid);
    }
    if (tid == 0) feat[row * 16 + 1] = __uint_as_float(madu);
}

// ---------- in-LDS bitonic sort of 512 floats, 256 threads ----------
__device__ void bitonic512(float* a, int tid) {
    for (int k = 2; k <= 512; k <<= 1) {
        for (int j = k >> 1; j > 0; j >>= 1) {
            __syncthreads();
            for (int i = tid; i < 512; i += 256) {
                int ixj = i ^ j;
                if (ixj > i) {
                    float x = a[i], y = a[ixj];
                    bool up = ((i & k) == 0);
                    if ((x > y) == up) { a[i] = y; a[ixj] = x; }
                }
            }
        }
    }
    __syncthreads();
}

// ---------- tail: b-row stats + MLP head fused, one block per (l,b) row ----------
__global__ __launch_bounds__(256) void tail_kernel(
    const float* __restrict__ bsrc, const float* __restrict__ feat,
    const float* __restrict__ fc1_w, const float* __restrict__ fc1_b,
    const float* __restrict__ ln_w,  const float* __restrict__ ln_b,
    const float* __restrict__ gate_w, const float* __restrict__ gate_b,
    const float* __restrict__ fco_w,  const float* __restrict__ fco_b,
    const float* __restrict__ scale,  float* __restrict__ out) {
    const int row = blockIdx.x;
    const int tid = threadIdx.x;
    const int l = row >> 6;
    __shared__ float a[512], d[512];
    __shared__ float x[16], h[64], hg[64], stats[2];

    // w-row features from global (written by wstats_kernel)
    if (tid < 7)       x[tid] = feat[row * 16 + tid];
    else if (tid == 7) x[14]  = feat[row * 16 + 14];
    else if (tid == 8) x[15]  = 0.0f;

    // b-row robust stats via bitonic sort
    const float* p = bsrc + (size_t)row * 512;
    for (int i = tid; i < 512; i += 256) a[i] = p[i];
    bitonic512(a, tid);
    const float bmed = a[255];
    if (tid == 0) {
        x[7]  = bmed;
        x[9]  = a[0];
        x[10] = 0.25f * a[127] + 0.75f * a[128];
        x[11] = 0.5f  * (a[255] + a[256]);
        x[12] = 0.75f * a[383] + 0.25f * a[384];
        x[13] = a[511];
    }
    __syncthreads();
    for (int i = tid; i < 512; i += 256) d[i] = fabsf(a[i] - bmed);
    bitonic512(d, tid);
    if (tid == 0) x[8] = d[255];
    __syncthreads();

    // LayerNorm(16) no affine
    if (tid == 0) {
        float mu = 0.f;
        for (int i = 0; i < 16; ++i) mu += x[i];
        mu *= (1.f / 16.f);
        float var = 0.f;
        for (int i = 0; i < 16; ++i) { float dd = x[i] - mu; var += dd * dd; }
        var *= (1.f / 16.f);
        stats[0] = mu; stats[1] = rsqrtf(var + 1e-5f);
    }
    __syncthreads();
    if (tid < 16) x[tid] = (x[tid] - stats[0]) * stats[1];
    __syncthreads();
    // fc1: 16 -> 64
    if (tid < 64) {
        const float* w = fc1_w + ((size_t)l * 64 + tid) * 16;
        float acc = fc1_b[l * 64 + tid];
        #pragma unroll
        for (int i = 0; i < 16; ++i) acc += x[i] * w[i];
        h[tid] = acc;
    }
    __syncthreads();
    // LayerNorm(64) with affine
    if (tid == 0) {
        float mu = 0.f;
        for (int i = 0; i < 64; ++i) mu += h[i];
        mu *= (1.f / 64.f);
        float var = 0.f;
        for (int i = 0; i < 64; ++i) { float dd = h[i] - mu; var += dd * dd; }
        var *= (1.f / 64.f);
        stats[0] = mu; stats[1] = rsqrtf(var + 1e-5f);
    }
    __syncthreads();
    if (tid < 64) {
        float v = (h[tid] - stats[0]) * stats[1] * ln_w[l * 64 + tid] + ln_b[l * 64 + tid];
        h[tid] = 0.5f * v * (1.0f + erff(v * 0.70710678118654752f));  // exact GELU
    }
    __syncthreads();
    // gate: sigmoid(h @ gate_w^T + b), then h * gate
    if (tid < 64) {
        const float* w = gate_w + ((size_t)l * 64 + tid) * 64;
        float acc = gate_b[l * 64 + tid];
        #pragma unroll
        for (int i = 0; i < 64; ++i) acc += h[i] * w[i];
        float g = 1.0f / (1.0f + expf(-acc));
        hg[tid] = h[tid] * g;
    }
    __syncthreads();
    // fco: 64 -> 512, sin * scale + 1
    const float sc = scale[l];
    for (int o = tid; o < 512; o += 256) {
        const float* w = fco_w + ((size_t)l * 512 + o) * 64;
        float acc = fco_b[l * 512 + o];
        #pragma unroll
        for (int i = 0; i < 64; ++i) acc += hg[i] * w[i];
        out[(size_t)row * 512 + o] = sinf(acc) * sc + 1.0f;
    }
}

extern "C" void kernel_launch(void* const* d_in, const int* in_sizes, int n_in,
                              void* d_out, int out_size, void* d_ws, size_t ws_size,
                              hipStream_t stream) {
    const float* ws_in  = (const float*)d_in[0];
    const float* bs_in  = (const float*)d_in[1];
    // d_in[2] (w_last) and d_in[3] (b_last) are unused by the reference.
    const float* fc1_w  = (const float*)d_in[4];
    const float* fc1_b  = (const float*)d_in[5];
    const float* ln_w   = (const float*)d_in[6];
    const float* ln_b   = (const float*)d_in[7];
    const float* gate_w = (const float*)d_in[8];
    const float* gate_b = (const float*)d_in[9];
    const float* fco_w  = (const float*)d_in[10];
    const float* fco_b  = (const float*)d_in[11];
    const float* scale  = (const float*)d_in[12];
    float* out  = (float*)d_out;
    float* feat = (float*)d_ws;   // 192 rows x 16 features

    hipLaunchKernelGGL(wstats_kernel, dim3(NROW), dim3(WT), 0, stream, ws_in, feat);
    hipLaunchKernelGGL(tail_kernel, dim3(NROW), dim3(256), 0, stream,
                       bs_in, feat, fc1_w, fc1_b, ln_w, ln_b, gate_w, gate_b,
                       fco_w, fco_b, scale, out);
}